// Round 10
// baseline (369.725 us; speedup 1.0000x reference)
//
#include <hip/hip_runtime.h>
#include <math.h>

// LSTMNextWindowPredictor via fp16 single-product MFMA: B=262144, I=13, H=64,
// T=5, O=13, fp32 in/out. Per wave: M=32 rows. Per t:
//   G[32x256] = X_t[32x15(pad32)] @ W_ih^T + H[32x64] @ W_hh^T
// via mfma_f32_16x16x32_f16 (fp32 accumulate), then elementwise LSTM update.
// h lives per-wave in LDS as fp16 in A-fragment k-contiguous layout (XOR
// swizzled by row&7) -> A-frag loads are pure ds_read_b128, no conversion.
// R6: LOG2E folded into prep-scaled weights; single-rcp fused sigmoid*tanh
// -> 7 trans ops/element (5 exp2 + 2 rcp). Algebraic floor for exact LSTM.
// R8/R13 lesson: ANY runtime index into a register array -> local memory.
// R13's '#pragma unroll 2' made jt=2*it+{0,1} runtime -> c_st to scratch
// (FETCH/WRITE +48MB, VGPR stuck 64). Full unroll keeps jt compile-time.
// R9: 512-thread blocks: whh(32K)+wih(8K)+hshm(8x4K)=72KB at 2 blocks/CU
// = 16 waves/CU (LDS-capped optimum; 640/384-thread variants lose to tail
// or wave-quantization). launch_bounds(512,4) -> 128 reg budget; VGPR=64.
// R10 lesson: LDS-staged epilogue + t=0 peel regressed (conflicts, icache).
// R11: bias rides wih k=13/k=14 channels (ZERO C-in first MFMA); x raw-f32
// prefetch one t ahead. R12: co-wave phase stagger = flat; reverted here.
// R14: jt loop FULLY unrolled: c_st statically indexed (registers, +32 regs
// is free under the 128 budget), all LDS offsets become compile-time
// immediates, and the scheduler may interleave jt+1's independent MFMA
// cluster into jt's transcendental burst (R13's intent, done legally).

#define TT 5
#define NI 13

typedef _Float16 half8 __attribute__((ext_vector_type(8)));
typedef __attribute__((ext_vector_type(4))) float f32x4;
typedef __attribute__((ext_vector_type(2))) float f32x2;

// ws byte offsets
#define WHH_OFF  0       // 16384 halves [kt2][nt16][lane64][j8]  (32 KB)
#define WIH_OFF  32768   // 4096 halves  [nt16][l32][j8]; k13=bias_hi k14=bias_lo
#define W1_OFF   40960   // 4096 halves  [kt2][nt4][lane64][j8]
#define W2_OFF   49152   // 1024 halves  [kt2][lane64][j8] (n>=13 zero)

#define LOG2E 1.44269504088896340736f
#define TWO_LOG2E 2.88539008177792681472f

// gate scale: n in [0,256); gate = n>>6 in {i,f,g,o}; g-gate scaled +2*log2e
// (tanh via e^{2g}), i/f/o scaled -log2e (sigmoid via e^{-v}).
__device__ __forceinline__ float gate_scale(int n) {
  return ((n >> 6) == 2) ? TWO_LOG2E : -LOG2E;
}

__device__ __forceinline__ f32x2 vexp2(f32x2 v) {
  f32x2 r;
  r[0] = __builtin_amdgcn_exp2f(v[0]);
  r[1] = __builtin_amdgcn_exp2f(v[1]);
  return r;
}
__device__ __forceinline__ f32x2 vrcp(f32x2 v) {
  f32x2 r;
  r[0] = __builtin_amdgcn_rcpf(v[0]);
  r[1] = __builtin_amdgcn_rcpf(v[1]);
  return r;
}

__global__ void prep_kernel(const float* __restrict__ W_ih,
                            const float* __restrict__ W_hh,
                            const float* __restrict__ b_ih,
                            const float* __restrict__ b_hh,
                            const float* __restrict__ W1,
                            const float* __restrict__ W2,
                            _Float16* __restrict__ whh,
                            _Float16* __restrict__ wih,
                            _Float16* __restrict__ w1,
                            _Float16* __restrict__ w2) {
  int idx = blockIdx.x * 256 + threadIdx.x;
  if (idx < 16384) {  // W_hh B-frags: B[k][n] = W_hh[n*64+k]
    int kt = idx >> 13, r = idx & 8191;
    int nt = r >> 9, lane = (r >> 3) & 63, j = idx & 7;
    int k = kt * 32 + ((lane >> 4) << 3) + j;
    int n = (nt << 4) + (lane & 15);
    whh[idx] = (_Float16)(W_hh[n * 64 + k] * gate_scale(n));
  }
  if (idx < 4096) {   // W_ih B-frags; k13 = bias hi, k14 = bias residual
    int nt = idx >> 8, l32 = (idx >> 3) & 31, j = idx & 7;
    int k = ((l32 >> 4) << 3) + j;
    int n = (nt << 4) + (l32 & 15);
    float v = 0.f;
    if (k < NI) {
      v = W_ih[n * NI + k] * gate_scale(n);
    } else if (k == NI) {          // bias, fp16 high part
      v = (b_ih[n] + b_hh[n]) * gate_scale(n);
    } else if (k == NI + 1) {      // bias residual (exactness to ~fp32)
      float b = (b_ih[n] + b_hh[n]) * gate_scale(n);
      v = b - (float)(_Float16)b;
    }
    wih[idx] = (_Float16)v;
  }
  if (idx < 4096) {   // W1 B-frags: B[k][n] = W1[n*64+k]
    int kt = idx >> 11, r = idx & 2047;
    int nt = r >> 9, lane = (r >> 3) & 63, j = idx & 7;
    int k = kt * 32 + ((lane >> 4) << 3) + j;
    int n = (nt << 4) + (lane & 15);
    w1[idx] = (_Float16)W1[n * 64 + k];
  }
  if (idx < 1024) {   // W2 B-frags (n>=13 zero)
    int kt = idx >> 9, lane = (idx >> 3) & 63, j = idx & 7;
    int k = kt * 32 + ((lane >> 4) << 3) + j;
    int n = lane & 15;
    w2[idx] = (_Float16)((n < 13) ? W2[n * 64 + k] : 0.f);
  }
}

// Read A-fragments (rows mt*16+mcol, k = kt*32+quad*8+j) from swizzled fp16 LDS.
__device__ __forceinline__ void read_afrags(const _Float16* __restrict__ hw,
                                            int quad, int mcol, half8 a[2][2]) {
#pragma unroll
  for (int mt = 0; mt < 2; ++mt) {
    const int r = mt * 16 + mcol;
#pragma unroll
    for (int kt = 0; kt < 2; ++kt) {
      const int blk = (kt * 4 + quad) ^ (r & 7);
      a[mt][kt] = *(const half8*)&hw[r * 64 + blk * 8];
    }
  }
}

__global__ __launch_bounds__(512, 4)
void lstm_mfma(const float* __restrict__ x,
               const _Float16* __restrict__ wm_g,   // whh + wih contiguous 40 KB
               const _Float16* __restrict__ w1_g,
               const _Float16* __restrict__ w2_g,
               const float* __restrict__ b1v,
               const float* __restrict__ b2v,
               float* __restrict__ out) {
  __shared__ __attribute__((aligned(16))) _Float16 wlds[20480];     // 40 KB: whh+wih
  __shared__ __attribute__((aligned(16))) _Float16 hshm[8][2048];   // 32 KB

  const int tid = threadIdx.x;
  const int wave = tid >> 6;
  const int lane = tid & 63;
  const int quad = lane >> 4;
  const int mcol = lane & 15;
  _Float16* __restrict__ hw = &hshm[wave][0];
  const int row0 = blockIdx.x * 256 + wave * 32;

  // stage whh+wih fragment tables into LDS (one-time, coalesced 16B)
  {
    const f32x4* __restrict__ s = (const f32x4*)wm_g;
    f32x4* d = (f32x4*)wlds;
#pragma unroll
    for (int i = 0; i < 5; ++i) d[tid + 512 * i] = s[tid + 512 * i];
  }
  __syncthreads();

  f32x2 c_st[2][4][2];  // [mt][jt][regpair] -- statically indexed everywhere
#pragma unroll
  for (int mt = 0; mt < 2; ++mt)
#pragma unroll
    for (int jt = 0; jt < 4; ++jt)
#pragma unroll
      for (int p = 0; p < 2; ++p) { c_st[mt][jt][p][0] = 0.f; c_st[mt][jt][p][1] = 0.f; }

  const half8* __restrict__ whhf = (const half8*)wlds;             // (kt*16+g*4+jt)*64+lane
  const half8* __restrict__ wihf = (const half8*)(wlds + 16384);   // (g*4+jt)*32+(lane&31)

  const f32x4 ZERO4 = {0.f, 0.f, 0.f, 0.f};

  const float* __restrict__ xp0 = x + (size_t)(row0 + mcol) * (TT * NI);
  const float* __restrict__ xp1 = x + (size_t)(row0 + 16 + mcol) * (TT * NI);

  // raw x prefetch registers (quad0: a=x[0:4) b=x[4:8); quad1: a=x[8:12) b.x=x12)
  f32x4 ra0, rb0, ra1, rb1;
  if (quad == 0) {
    __builtin_memcpy(&ra0, xp0, 16);  __builtin_memcpy(&rb0, xp0 + 4, 16);
    __builtin_memcpy(&ra1, xp1, 16);  __builtin_memcpy(&rb1, xp1 + 4, 16);
  } else if (quad == 1) {
    __builtin_memcpy(&ra0, xp0 + 8, 16);  rb0[0] = xp0[12];
    __builtin_memcpy(&ra1, xp1 + 8, 16);  rb1[0] = xp1[12];
  }

#pragma unroll 1
  for (int t = 0; t < TT; ++t) {
    // convert prefetched raw -> xa frags (k = quad*8+j; k13,k14 = 1.0 bias ch.)
    half8 xa0, xa1;
    {
      half8 v0, v1;
#pragma unroll
      for (int j = 0; j < 8; ++j) { v0[j] = (_Float16)0.f; v1[j] = (_Float16)0.f; }
      if (quad == 0) {
#pragma unroll
        for (int j = 0; j < 4; ++j) {
          v0[j] = (_Float16)ra0[j]; v0[4 + j] = (_Float16)rb0[j];
          v1[j] = (_Float16)ra1[j]; v1[4 + j] = (_Float16)rb1[j];
        }
      } else if (quad == 1) {
#pragma unroll
        for (int j = 0; j < 4; ++j) { v0[j] = (_Float16)ra0[j]; v1[j] = (_Float16)ra1[j]; }
        v0[4] = (_Float16)rb0[0];  v1[4] = (_Float16)rb1[0];
        v0[5] = (_Float16)1.f;     v1[5] = (_Float16)1.f;   // k=13 bias hi
        v0[6] = (_Float16)1.f;     v1[6] = (_Float16)1.f;   // k=14 bias lo
      }
      xa0 = v0; xa1 = v1;
    }

    // issue next-t raw loads early (consumed after the full jt loop)
    if (t + 1 < TT) {
      const float* __restrict__ q0 = xp0 + (t + 1) * NI;
      const float* __restrict__ q1 = xp1 + (t + 1) * NI;
      if (quad == 0) {
        __builtin_memcpy(&ra0, q0, 16);  __builtin_memcpy(&rb0, q0 + 4, 16);
        __builtin_memcpy(&ra1, q1, 16);  __builtin_memcpy(&rb1, q1 + 4, 16);
      } else if (quad == 1) {
        __builtin_memcpy(&ra0, q0 + 8, 16);  rb0[0] = q0[12];
        __builtin_memcpy(&ra1, q1 + 8, 16);  rb1[0] = q1[12];
      }
    }

    half8 ah[2][2];
    if (t > 0) read_afrags(hw, quad, mcol, ah);

    // FULL unroll: jt compile-time in all bodies -> c_st in registers,
    // LDS offsets become immediates, scheduler may interleave jt+1's
    // MFMA cluster into jt's transcendental burst.
#pragma unroll
    for (int jt = 0; jt < 4; ++jt) {
      f32x4 acc[2][4];

      // x @ W_ih^T (+bias channels); first MFMA takes shared ZERO quad as C
#pragma unroll
      for (int g = 0; g < 4; ++g) {
        const half8 bfr = wihf[(g * 4 + jt) * 32 + (lane & 31)];
        acc[0][g] = __builtin_amdgcn_mfma_f32_16x16x32_f16(xa0, bfr, ZERO4, 0, 0, 0);
        acc[1][g] = __builtin_amdgcn_mfma_f32_16x16x32_f16(xa1, bfr, ZERO4, 0, 0, 0);
      }

      // h @ W_hh^T (h==0 at t=0), B-frags from LDS
      if (t > 0) {
#pragma unroll
        for (int kt = 0; kt < 2; ++kt)
#pragma unroll
          for (int g = 0; g < 4; ++g) {
            const half8 bfr = whhf[(kt * 16 + g * 4 + jt) * 64 + lane];
#pragma unroll
            for (int mt = 0; mt < 2; ++mt)
              acc[mt][g] = __builtin_amdgcn_mfma_f32_16x16x32_f16(ah[mt][kt], bfr, acc[mt][g], 0, 0, 0);
          }
      }

      // elementwise LSTM update over reg-pairs (v_pk_*_f32); lane owns rows
      // quad*4+reg, col jt*16+mcol. accs pre-scaled: si=-log2e*i, sf=-log2e*f,
      // sg=2log2e*g, so=-log2e*o
#pragma unroll
      for (int mt = 0; mt < 2; ++mt)
#pragma unroll
        for (int p = 0; p < 2; ++p) {
          f32x2 si = {acc[mt][0][p * 2], acc[mt][0][p * 2 + 1]};
          f32x2 sf = {acc[mt][1][p * 2], acc[mt][1][p * 2 + 1]};
          f32x2 sg = {acc[mt][2][p * 2], acc[mt][2][p * 2 + 1]};
          f32x2 so = {acc[mt][3][p * 2], acc[mt][3][p * 2 + 1]};
          const f32x2 A  = vexp2(sf);   // e^{-f}
          const f32x2 Bv = vexp2(si);   // e^{-i}
          const f32x2 E  = vexp2(sg);   // e^{2g}
          const f32x2 pA = 1.f + A;
          const f32x2 pB = 1.f + Bv;
          const f32x2 ep = E + 1.f;
          const f32x2 em = E - 1.f;
          const f32x2 m1 = pB * ep;
          f32x2 cv = c_st[mt][jt][p];
          const f32x2 num = cv * m1 + em * pA;   // contracts to v_pk_fma_f32
          cv = num * vrcp(pA * m1);
          c_st[mt][jt][p] = cv;
          const f32x2 C2 = vexp2(so);               // e^{-o}
          const f32x2 F  = vexp2(cv * TWO_LOG2E);   // e^{2c}
          const f32x2 hn = (F - 1.f) * vrcp((1.f + C2) * (F + 1.f));
#pragma unroll
          for (int u = 0; u < 2; ++u) {
            const int r = mt * 16 + quad * 4 + p * 2 + u;
            const int k = jt * 16 + mcol;
            hw[r * 64 + (((k >> 3) ^ (r & 7)) << 3) + (k & 7)] = (_Float16)hn[u];
          }
        }
    }
  }

  // ---- head: z = relu(h @ W1^T + b1), fp16 round-trip through LDS ----
  {
    half8 ah[2][2];
    read_afrags(hw, quad, mcol, ah);

    f32x4 zacc[2][4];
#pragma unroll
    for (int nt = 0; nt < 4; ++nt) {
      const float b = b1v[nt * 16 + mcol];
#pragma unroll
      for (int mt = 0; mt < 2; ++mt) {
        f32x4 z = {b, b, b, b};
        zacc[mt][nt] = z;
      }
    }
#pragma unroll
    for (int kt = 0; kt < 2; ++kt)
#pragma unroll
      for (int nt = 0; nt < 4; ++nt) {
        const half8 bfr = ((const half8*)w1_g)[(kt * 4 + nt) * 64 + lane];
#pragma unroll
        for (int mt = 0; mt < 2; ++mt)
          zacc[mt][nt] = __builtin_amdgcn_mfma_f32_16x16x32_f16(ah[mt][kt], bfr, zacc[mt][nt], 0, 0, 0);
      }
#pragma unroll
    for (int mt = 0; mt < 2; ++mt)
#pragma unroll
      for (int nt = 0; nt < 4; ++nt)
#pragma unroll
        for (int reg = 0; reg < 4; ++reg) {
          const float zv = fmaxf(zacc[mt][nt][reg], 0.f);
          const int r = mt * 16 + quad * 4 + reg;
          const int k = nt * 16 + mcol;
          hw[r * 64 + (((k >> 3) ^ (r & 7)) << 3) + (k & 7)] = (_Float16)zv;
        }
  }

  // ---- head: out = z @ W2^T + b2 ----
  {
    half8 zh[2][2];
    read_afrags(hw, quad, mcol, zh);

    const float b2r = (mcol < 13) ? b2v[mcol] : 0.f;
    f32x4 oacc[2];
#pragma unroll
    for (int mt = 0; mt < 2; ++mt) {
      f32x4 z = {b2r, b2r, b2r, b2r};
      oacc[mt] = z;
    }
#pragma unroll
    for (int kt = 0; kt < 2; ++kt) {
      const half8 bfr = ((const half8*)w2_g)[kt * 64 + lane];
#pragma unroll
      for (int mt = 0; mt < 2; ++mt)
        oacc[mt] = __builtin_amdgcn_mfma_f32_16x16x32_f16(zh[mt][kt], bfr, oacc[mt], 0, 0, 0);
    }
    if (mcol < 13) {
#pragma unroll
      for (int mt = 0; mt < 2; ++mt)
#pragma unroll
        for (int reg = 0; reg < 4; ++reg) {
          const int row = row0 + mt * 16 + quad * 4 + reg;
          out[row * 13 + mcol] = oacc[mt][reg];
        }
    }
  }
}

extern "C" void kernel_launch(void* const* d_in, const int* in_sizes, int n_in,
                              void* d_out, int out_size, void* d_ws, size_t ws_size,
                              hipStream_t stream) {
  const float* x    = (const float*)d_in[0];
  const float* W_ih = (const float*)d_in[1];
  const float* W_hh = (const float*)d_in[2];
  const float* b_ih = (const float*)d_in[3];
  const float* b_hh = (const float*)d_in[4];
  const float* W1   = (const float*)d_in[5];
  const float* b1   = (const float*)d_in[6];
  const float* W2   = (const float*)d_in[7];
  const float* b2   = (const float*)d_in[8];
  float* out = (float*)d_out;
  char* ws = (char*)d_ws;

  _Float16* whh = (_Float16*)(ws + WHH_OFF);
  _Float16* wih = (_Float16*)(ws + WIH_OFF);
  _Float16* w1  = (_Float16*)(ws + W1_OFF);
  _Float16* w2  = (_Float16*)(ws + W2_OFF);

  hipLaunchKernelGGL(prep_kernel, dim3(64), dim3(256), 0, stream,
                     W_ih, W_hh, b_ih, b_hh, W1, W2, whh, wih, w1, w2);

  const int B = in_sizes[0] / (TT * NI);  // 262144
  hipLaunchKernelGGL(lstm_mfma, dim3(B / 256), dim3(512), 0, stream,
                     x, whh, w1, w2, b1, b2, out);
}

// Round 11
// 218.262 us; speedup vs baseline: 1.6939x; 1.6939x over previous
//
#include <hip/hip_runtime.h>
#include <math.h>

// LSTMNextWindowPredictor via fp16 single-product MFMA: B=262144, I=13, H=64,
// T=5, O=13, fp32 in/out. Per wave: M=32 rows. Per t:
//   G[32x256] = X_t[32x15(pad32)] @ W_ih^T + H[32x64] @ W_hh^T
// via mfma_f32_16x16x32_f16 (fp32 accumulate), then elementwise LSTM update.
// h lives per-wave in LDS as fp16 in A-fragment k-contiguous layout (XOR
// swizzled by row&7) -> A-frag loads are pure ds_read_b128, no conversion.
// R6: LOG2E folded into prep-scaled weights; single-rcp fused sigmoid*tanh
// -> 7 trans ops/element (5 exp2 + 2 rcp). Algebraic floor for exact LSTM.
// R9: 512-thread blocks: whh(32K)+wih(8K)+hshm(8x4K)=72KB at 2 blocks/CU
// = 16 waves/CU with ALL weights in LDS (conflict-free ds_read_b128).
// R11: bias rides wih k=13/k=14 channels (ZERO C-in first MFMA); x raw-f32
// prefetch one t ahead.
// REGISTER WALL (R7/R13/R14, three independent confirmations): compiler
// splits the unified file at accum_offset=64 (64 arch VGPR + 64 AGPR) and
// SPILLS rather than re-split. Usable arch-VGPR budget is 64. Any unroll
// or extra live state beyond the current structure -> scratch (R13 +48MB,
// R14 +780MB traffic). Keep '#pragma unroll 1' on the jt loop; keep all
// register-array indices compile-time; do not add live state.
// Other measured dead ends: global weights (R5: L2 thrash), LDS-staged
// epilogue + t=0 peel (R10), co-wave phase stagger (R12: flat, kept -
// this is the verbatim best-measured round-8 source).

#define TT 5
#define NI 13

typedef _Float16 half8 __attribute__((ext_vector_type(8)));
typedef __attribute__((ext_vector_type(4))) float f32x4;
typedef __attribute__((ext_vector_type(2))) float f32x2;

// ws byte offsets
#define WHH_OFF  0       // 16384 halves [kt2][nt16][lane64][j8]  (32 KB)
#define WIH_OFF  32768   // 4096 halves  [nt16][l32][j8]; k13=bias_hi k14=bias_lo
#define W1_OFF   40960   // 4096 halves  [kt2][nt4][lane64][j8]
#define W2_OFF   49152   // 1024 halves  [kt2][lane64][j8] (n>=13 zero)

#define LOG2E 1.44269504088896340736f
#define TWO_LOG2E 2.88539008177792681472f

// gate scale: n in [0,256); gate = n>>6 in {i,f,g,o}; g-gate scaled +2*log2e
// (tanh via e^{2g}), i/f/o scaled -log2e (sigmoid via e^{-v}).
__device__ __forceinline__ float gate_scale(int n) {
  return ((n >> 6) == 2) ? TWO_LOG2E : -LOG2E;
}

__device__ __forceinline__ f32x2 vexp2(f32x2 v) {
  f32x2 r;
  r[0] = __builtin_amdgcn_exp2f(v[0]);
  r[1] = __builtin_amdgcn_exp2f(v[1]);
  return r;
}
__device__ __forceinline__ f32x2 vrcp(f32x2 v) {
  f32x2 r;
  r[0] = __builtin_amdgcn_rcpf(v[0]);
  r[1] = __builtin_amdgcn_rcpf(v[1]);
  return r;
}

__global__ void prep_kernel(const float* __restrict__ W_ih,
                            const float* __restrict__ W_hh,
                            const float* __restrict__ b_ih,
                            const float* __restrict__ b_hh,
                            const float* __restrict__ W1,
                            const float* __restrict__ W2,
                            _Float16* __restrict__ whh,
                            _Float16* __restrict__ wih,
                            _Float16* __restrict__ w1,
                            _Float16* __restrict__ w2) {
  int idx = blockIdx.x * 256 + threadIdx.x;
  if (idx < 16384) {  // W_hh B-frags: B[k][n] = W_hh[n*64+k]
    int kt = idx >> 13, r = idx & 8191;
    int nt = r >> 9, lane = (r >> 3) & 63, j = idx & 7;
    int k = kt * 32 + ((lane >> 4) << 3) + j;
    int n = (nt << 4) + (lane & 15);
    whh[idx] = (_Float16)(W_hh[n * 64 + k] * gate_scale(n));
  }
  if (idx < 4096) {   // W_ih B-frags; k13 = bias hi, k14 = bias residual
    int nt = idx >> 8, l32 = (idx >> 3) & 31, j = idx & 7;
    int k = ((l32 >> 4) << 3) + j;
    int n = (nt << 4) + (l32 & 15);
    float v = 0.f;
    if (k < NI) {
      v = W_ih[n * NI + k] * gate_scale(n);
    } else if (k == NI) {          // bias, fp16 high part
      v = (b_ih[n] + b_hh[n]) * gate_scale(n);
    } else if (k == NI + 1) {      // bias residual (exactness to ~fp32)
      float b = (b_ih[n] + b_hh[n]) * gate_scale(n);
      v = b - (float)(_Float16)b;
    }
    wih[idx] = (_Float16)v;
  }
  if (idx < 4096) {   // W1 B-frags: B[k][n] = W1[n*64+k]
    int kt = idx >> 11, r = idx & 2047;
    int nt = r >> 9, lane = (r >> 3) & 63, j = idx & 7;
    int k = kt * 32 + ((lane >> 4) << 3) + j;
    int n = (nt << 4) + (lane & 15);
    w1[idx] = (_Float16)W1[n * 64 + k];
  }
  if (idx < 1024) {   // W2 B-frags (n>=13 zero)
    int kt = idx >> 9, lane = (idx >> 3) & 63, j = idx & 7;
    int k = kt * 32 + ((lane >> 4) << 3) + j;
    int n = lane & 15;
    w2[idx] = (_Float16)((n < 13) ? W2[n * 64 + k] : 0.f);
  }
}

// Read A-fragments (rows mt*16+mcol, k = kt*32+quad*8+j) from swizzled fp16 LDS.
__device__ __forceinline__ void read_afrags(const _Float16* __restrict__ hw,
                                            int quad, int mcol, half8 a[2][2]) {
#pragma unroll
  for (int mt = 0; mt < 2; ++mt) {
    const int r = mt * 16 + mcol;
#pragma unroll
    for (int kt = 0; kt < 2; ++kt) {
      const int blk = (kt * 4 + quad) ^ (r & 7);
      a[mt][kt] = *(const half8*)&hw[r * 64 + blk * 8];
    }
  }
}

__global__ __launch_bounds__(512, 4)
void lstm_mfma(const float* __restrict__ x,
               const _Float16* __restrict__ wm_g,   // whh + wih contiguous 40 KB
               const _Float16* __restrict__ w1_g,
               const _Float16* __restrict__ w2_g,
               const float* __restrict__ b1v,
               const float* __restrict__ b2v,
               float* __restrict__ out) {
  __shared__ __attribute__((aligned(16))) _Float16 wlds[20480];     // 40 KB: whh+wih
  __shared__ __attribute__((aligned(16))) _Float16 hshm[8][2048];   // 32 KB

  const int tid = threadIdx.x;
  const int wave = tid >> 6;
  const int lane = tid & 63;
  const int quad = lane >> 4;
  const int mcol = lane & 15;
  _Float16* __restrict__ hw = &hshm[wave][0];
  const int row0 = blockIdx.x * 256 + wave * 32;

  // gate-block stagger (R12; measured neutral, kept as part of the
  // verbatim best-measured configuration)
  const int sgg = ((wave ^ (wave >> 2)) & 1) << 1;

  // stage whh+wih fragment tables into LDS (one-time, coalesced 16B)
  {
    const f32x4* __restrict__ s = (const f32x4*)wm_g;
    f32x4* d = (f32x4*)wlds;
#pragma unroll
    for (int i = 0; i < 5; ++i) d[tid + 512 * i] = s[tid + 512 * i];
  }
  __syncthreads();

  f32x2 c_st[2][4][2];  // [mt][jt][regpair]  (jt = loop slot, maps to gb=jt^sgg)
#pragma unroll
  for (int mt = 0; mt < 2; ++mt)
#pragma unroll
    for (int jt = 0; jt < 4; ++jt)
#pragma unroll
      for (int p = 0; p < 2; ++p) { c_st[mt][jt][p][0] = 0.f; c_st[mt][jt][p][1] = 0.f; }

  const half8* __restrict__ whhf = (const half8*)wlds;             // (kt*16+g*4+gb)*64+lane
  const half8* __restrict__ wihf = (const half8*)(wlds + 16384);   // (g*4+gb)*32+(lane&31)

  const f32x4 ZERO4 = {0.f, 0.f, 0.f, 0.f};

  const float* __restrict__ xp0 = x + (size_t)(row0 + mcol) * (TT * NI);
  const float* __restrict__ xp1 = x + (size_t)(row0 + 16 + mcol) * (TT * NI);

  // raw x prefetch registers (quad0: a=x[0:4) b=x[4:8); quad1: a=x[8:12) b.x=x12)
  f32x4 ra0, rb0, ra1, rb1;
  if (quad == 0) {
    __builtin_memcpy(&ra0, xp0, 16);  __builtin_memcpy(&rb0, xp0 + 4, 16);
    __builtin_memcpy(&ra1, xp1, 16);  __builtin_memcpy(&rb1, xp1 + 4, 16);
  } else if (quad == 1) {
    __builtin_memcpy(&ra0, xp0 + 8, 16);  rb0[0] = xp0[12];
    __builtin_memcpy(&ra1, xp1 + 8, 16);  rb1[0] = xp1[12];
  }

#pragma unroll 1
  for (int t = 0; t < TT; ++t) {
    // convert prefetched raw -> xa frags (k = quad*8+j; k13,k14 = 1.0 bias ch.)
    half8 xa0, xa1;
    {
      half8 v0, v1;
#pragma unroll
      for (int j = 0; j < 8; ++j) { v0[j] = (_Float16)0.f; v1[j] = (_Float16)0.f; }
      if (quad == 0) {
#pragma unroll
        for (int j = 0; j < 4; ++j) {
          v0[j] = (_Float16)ra0[j]; v0[4 + j] = (_Float16)rb0[j];
          v1[j] = (_Float16)ra1[j]; v1[4 + j] = (_Float16)rb1[j];
        }
      } else if (quad == 1) {
#pragma unroll
        for (int j = 0; j < 4; ++j) { v0[j] = (_Float16)ra0[j]; v1[j] = (_Float16)ra1[j]; }
        v0[4] = (_Float16)rb0[0];  v1[4] = (_Float16)rb1[0];
        v0[5] = (_Float16)1.f;     v1[5] = (_Float16)1.f;   // k=13 bias hi
        v0[6] = (_Float16)1.f;     v1[6] = (_Float16)1.f;   // k=14 bias lo
      }
      xa0 = v0; xa1 = v1;
    }

    // issue next-t raw loads early (consumed after the full jt loop)
    if (t + 1 < TT) {
      const float* __restrict__ q0 = xp0 + (t + 1) * NI;
      const float* __restrict__ q1 = xp1 + (t + 1) * NI;
      if (quad == 0) {
        __builtin_memcpy(&ra0, q0, 16);  __builtin_memcpy(&rb0, q0 + 4, 16);
        __builtin_memcpy(&ra1, q1, 16);  __builtin_memcpy(&rb1, q1 + 4, 16);
      } else if (quad == 1) {
        __builtin_memcpy(&ra0, q0 + 8, 16);  rb0[0] = q0[12];
        __builtin_memcpy(&ra1, q1 + 8, 16);  rb1[0] = q1[12];
      }
    }

    half8 ah[2][2];
    if (t > 0) read_afrags(hw, quad, mcol, ah);

#pragma unroll 1
    for (int jt = 0; jt < 4; ++jt) {
      const int gb = jt ^ sgg;   // gate-block handled at this loop slot
      f32x4 acc[2][4];

      // x @ W_ih^T (+bias channels); first MFMA takes shared ZERO quad as C
#pragma unroll
      for (int g = 0; g < 4; ++g) {
        const half8 bfr = wihf[(g * 4 + gb) * 32 + (lane & 31)];
        acc[0][g] = __builtin_amdgcn_mfma_f32_16x16x32_f16(xa0, bfr, ZERO4, 0, 0, 0);
        acc[1][g] = __builtin_amdgcn_mfma_f32_16x16x32_f16(xa1, bfr, ZERO4, 0, 0, 0);
      }

      // h @ W_hh^T (h==0 at t=0), B-frags from LDS
      if (t > 0) {
#pragma unroll
        for (int kt = 0; kt < 2; ++kt)
#pragma unroll
          for (int g = 0; g < 4; ++g) {
            const half8 bfr = whhf[(kt * 16 + g * 4 + gb) * 64 + lane];
#pragma unroll
            for (int mt = 0; mt < 2; ++mt)
              acc[mt][g] = __builtin_amdgcn_mfma_f32_16x16x32_f16(ah[mt][kt], bfr, acc[mt][g], 0, 0, 0);
          }
      }

      // elementwise LSTM update over reg-pairs (v_pk_*_f32); lane owns rows
      // quad*4+reg, col gb*16+mcol. accs pre-scaled: si=-log2e*i, sf=-log2e*f,
      // sg=2log2e*g, so=-log2e*o
#pragma unroll
      for (int mt = 0; mt < 2; ++mt)
#pragma unroll
        for (int p = 0; p < 2; ++p) {
          f32x2 si = {acc[mt][0][p * 2], acc[mt][0][p * 2 + 1]};
          f32x2 sf = {acc[mt][1][p * 2], acc[mt][1][p * 2 + 1]};
          f32x2 sg = {acc[mt][2][p * 2], acc[mt][2][p * 2 + 1]};
          f32x2 so = {acc[mt][3][p * 2], acc[mt][3][p * 2 + 1]};
          const f32x2 A  = vexp2(sf);   // e^{-f}
          const f32x2 Bv = vexp2(si);   // e^{-i}
          const f32x2 E  = vexp2(sg);   // e^{2g}
          const f32x2 pA = 1.f + A;
          const f32x2 pB = 1.f + Bv;
          const f32x2 ep = E + 1.f;
          const f32x2 em = E - 1.f;
          const f32x2 m1 = pB * ep;
          f32x2 cv = c_st[mt][jt][p];
          const f32x2 num = cv * m1 + em * pA;   // contracts to v_pk_fma_f32
          cv = num * vrcp(pA * m1);
          c_st[mt][jt][p] = cv;
          const f32x2 C2 = vexp2(so);               // e^{-o}
          const f32x2 F  = vexp2(cv * TWO_LOG2E);   // e^{2c}
          const f32x2 hn = (F - 1.f) * vrcp((1.f + C2) * (F + 1.f));
#pragma unroll
          for (int u = 0; u < 2; ++u) {
            const int r = mt * 16 + quad * 4 + p * 2 + u;
            const int k = gb * 16 + mcol;
            hw[r * 64 + (((k >> 3) ^ (r & 7)) << 3) + (k & 7)] = (_Float16)hn[u];
          }
        }
    }
  }

  // ---- head: z = relu(h @ W1^T + b1), fp16 round-trip through LDS ----
  {
    half8 ah[2][2];
    read_afrags(hw, quad, mcol, ah);

    f32x4 zacc[2][4];
#pragma unroll
    for (int nt = 0; nt < 4; ++nt) {
      const float b = b1v[nt * 16 + mcol];
#pragma unroll
      for (int mt = 0; mt < 2; ++mt) {
        f32x4 z = {b, b, b, b};
        zacc[mt][nt] = z;
      }
    }
#pragma unroll
    for (int kt = 0; kt < 2; ++kt)
#pragma unroll
      for (int nt = 0; nt < 4; ++nt) {
        const half8 bfr = ((const half8*)w1_g)[(kt * 4 + nt) * 64 + lane];
#pragma unroll
        for (int mt = 0; mt < 2; ++mt)
          zacc[mt][nt] = __builtin_amdgcn_mfma_f32_16x16x32_f16(ah[mt][kt], bfr, zacc[mt][nt], 0, 0, 0);
      }
#pragma unroll
    for (int mt = 0; mt < 2; ++mt)
#pragma unroll
      for (int nt = 0; nt < 4; ++nt)
#pragma unroll
        for (int reg = 0; reg < 4; ++reg) {
          const float zv = fmaxf(zacc[mt][nt][reg], 0.f);
          const int r = mt * 16 + quad * 4 + reg;
          const int k = nt * 16 + mcol;
          hw[r * 64 + (((k >> 3) ^ (r & 7)) << 3) + (k & 7)] = (_Float16)zv;
        }
  }

  // ---- head: out = z @ W2^T + b2 ----
  {
    half8 zh[2][2];
    read_afrags(hw, quad, mcol, zh);

    const float b2r = (mcol < 13) ? b2v[mcol] : 0.f;
    f32x4 oacc[2];
#pragma unroll
    for (int mt = 0; mt < 2; ++mt) {
      f32x4 z = {b2r, b2r, b2r, b2r};
      oacc[mt] = z;
    }
#pragma unroll
    for (int kt = 0; kt < 2; ++kt) {
      const half8 bfr = ((const half8*)w2_g)[kt * 64 + lane];
#pragma unroll
      for (int mt = 0; mt < 2; ++mt)
        oacc[mt] = __builtin_amdgcn_mfma_f32_16x16x32_f16(zh[mt][kt], bfr, oacc[mt], 0, 0, 0);
    }
    if (mcol < 13) {
#pragma unroll
      for (int mt = 0; mt < 2; ++mt)
#pragma unroll
        for (int reg = 0; reg < 4; ++reg) {
          const int row = row0 + mt * 16 + quad * 4 + reg;
          out[row * 13 + mcol] = oacc[mt][reg];
        }
    }
  }
}

extern "C" void kernel_launch(void* const* d_in, const int* in_sizes, int n_in,
                              void* d_out, int out_size, void* d_ws, size_t ws_size,
                              hipStream_t stream) {
  const float* x    = (const float*)d_in[0];
  const float* W_ih = (const float*)d_in[1];
  const float* W_hh = (const float*)d_in[2];
  const float* b_ih = (const float*)d_in[3];
  const float* b_hh = (const float*)d_in[4];
  const float* W1   = (const float*)d_in[5];
  const float* b1   = (const float*)d_in[6];
  const float* W2   = (const float*)d_in[7];
  const float* b2   = (const float*)d_in[8];
  float* out = (float*)d_out;
  char* ws = (char*)d_ws;

  _Float16* whh = (_Float16*)(ws + WHH_OFF);
  _Float16* wih = (_Float16*)(ws + WIH_OFF);
  _Float16* w1  = (_Float16*)(ws + W1_OFF);
  _Float16* w2  = (_Float16*)(ws + W2_OFF);

  hipLaunchKernelGGL(prep_kernel, dim3(64), dim3(256), 0, stream,
                     W_ih, W_hh, b_ih, b_hh, W1, W2, whh, wih, w1, w2);

  const int B = in_sizes[0] / (TT * NI);  // 262144
  hipLaunchKernelGGL(lstm_mfma, dim3(B / 256), dim3(512), 0, stream,
                     x, whh, w1, w2, b1, b2, out);
}